// Round 13
// baseline (54.021 us; speedup 1.0000x reference)
//
#include <hip/hip_runtime.h>
#include <hip/hip_bf16.h>

// SiameseConv — R13 = PHASE ABLATION PROBE.
// Correct path = R10's verified siamese+reduce (unchanged). Added 4x
// stage_only (staging phase exact copy, asm-keepalive so LDS writes stay
// live, no global writes). T_stage = (dur - 21.9)/4 - 1.85(node).
// Pre-committed: dur 75-85 -> staging-bound (fix fetch/pipeline);
// dur 45-52 -> compute/LDS-read-bound (fix A-frag access pattern).
// History: R2 atomics -18us; R7 bf16 ws -1us; R4/5/6/10/12 structural nulls;
// R9 fences 7x disaster; R11 probe: reduce+node = 2.67us.

typedef __bf16 bf16x8 __attribute__((ext_vector_type(8)));
typedef float f32x4 __attribute__((ext_vector_type(4)));

#define NB 64
#define C_TOT 256
#define CQ 32            // channels per block
#define NQ 8             // c-chunks
#define NPOS 400         // 20*20 det positions
#define NP 289           // 17*17 output positions
#define NPP 296          // padded p stride in bf16 partials
#define NO 20            // outputs per position
#define OPAD 20          // o rows in LDS tmpl tile
#define QSTRIDE (NB * NO * NPP)             // elems per q slice = 378880
#define DET_LDS_BYTES (NPOS * CQ * 2)       // 25600: [400 pos][32 c]
#define TMP_LDS_BYTES (16 * OPAD * CQ * 2)  // 20480: [16 ij][20 o][32 c]

__device__ __forceinline__ unsigned short bfbits(float f) {
  __bf16 h = (__bf16)f;
  return __builtin_bit_cast(unsigned short, h);
}
__device__ __forceinline__ unsigned pk2(float a, float b) {
  return (unsigned)bfbits(a) | ((unsigned)bfbits(b) << 16);
}
__device__ __forceinline__ float lo2f(unsigned u) {
  return __builtin_bit_cast(float, u << 16);
}
__device__ __forceinline__ float hi2f(unsigned u) {
  return __builtin_bit_cast(float, u & 0xFFFF0000u);
}

// ---- reduce: out[b,p,o] = sum_q bf16 ws[q,b,o,p]; transpose via LDS ----
__global__ __launch_bounds__(256)
void reduce_kernel(const unsigned short* __restrict__ ws, float* __restrict__ out) {
  __shared__ float sbuf[NO * 80];   // [o][80 p]
  const int b    = blockIdx.x >> 2;
  const int pg   = blockIdx.x & 3;
  const int p0g  = pg * 80;
  const int np   = (NP - p0g < 80) ? (NP - p0g) : 80;   // 80,80,80,49
  const int noct = (np + 7) >> 3;                       // 10 or 7
  const int units = NO * noct;                          // 200 or 140

  const int t = threadIdx.x;
  if (t < units) {
    int o  = t / noct;
    int po = t - o * noct;
    const unsigned short* src = ws + ((size_t)b * NO + o) * NPP + p0g + po * 8;
    float s[8] = {0, 0, 0, 0, 0, 0, 0, 0};
    #pragma unroll
    for (int q = 0; q < NQ; ++q) {
      uint4 v = *(const uint4*)(src + (size_t)q * QSTRIDE);
      s[0] += lo2f(v.x); s[1] += hi2f(v.x);
      s[2] += lo2f(v.y); s[3] += hi2f(v.y);
      s[4] += lo2f(v.z); s[5] += hi2f(v.z);
      s[6] += lo2f(v.w); s[7] += hi2f(v.w);
    }
    #pragma unroll
    for (int j = 0; j < 8; ++j) sbuf[o * 80 + po * 8 + j] = s[j];
  }
  __syncthreads();

  for (int p = t; p < np; p += 256) {
    float* dst = out + (size_t)b * (NP * NO) + (p0g + p) * NO;
    #pragma unroll
    for (int k = 0; k < 5; ++k) {
      f32x4 v;
      #pragma unroll
      for (int j = 0; j < 4; ++j) v[j] = sbuf[(k * 4 + j) * 80 + p];
      *(f32x4*)(dst + k * 4) = v;
    }
  }
}

__global__ __launch_bounds__(512, 2)
void siamese_kernel(const float* __restrict__ det,
                    const float* __restrict__ tmp,
                    unsigned short* __restrict__ ws) {
  __shared__ alignas(16) char lds[DET_LDS_BYTES + TMP_LDS_BYTES];
  char* detB = lds;
  char* tmpB = lds + DET_LDS_BYTES;

  const int tid = threadIdx.x;
  const int b   = blockIdx.x >> 3;
  const int q   = blockIdx.x & 7;
  const int c0  = q * CQ;

  const float* __restrict__ dsrc = det + (size_t)b * (NPOS * C_TOT) + c0;
  const float* __restrict__ tsrc = tmp + (size_t)b * (16 * C_TOT * NO);

  // ==== BURST STAGING ====
  float4 dva[4][2];
  int dpos[4] = {0, 0, 0, 0}, dcp[4] = {0, 0, 0, 0};
  #pragma unroll
  for (int k = 0; k < 3; ++k) {
    int u = tid + k * 512;
    dpos[k] = u >> 2; dcp[k] = u & 3;
    const float* s = dsrc + dpos[k] * C_TOT + dcp[k] * 8;
    dva[k][0] = *(const float4*)s;
    dva[k][1] = *(const float4*)(s + 4);
  }
  if (tid < 64) {
    int u = 1536 + tid;
    dpos[3] = u >> 2; dcp[3] = u & 3;
    const float* s = dsrc + dpos[3] * C_TOT + dcp[3] * 8;
    dva[3][0] = *(const float4*)s;
    dva[3][1] = *(const float4*)(s + 4);
  }
  int t_ij = 0, t_co = 0, t_oq = 0;
  float4 tv[8];
  if (tid < 320) {
    t_ij = tid / 20;
    int r = tid - t_ij * 20;
    t_co = r / 5;
    t_oq = r - t_co * 5;
    const float* s = tsrc + t_ij * (C_TOT * NO) + (c0 + t_co * 8) * NO + t_oq * 4;
    #pragma unroll
    for (int rr = 0; rr < 8; ++rr) tv[rr] = *(const float4*)(s + rr * NO);
  }

  #pragma unroll
  for (int k = 0; k < 3; ++k) {
    uint4 w = { pk2(dva[k][0].x, dva[k][0].y), pk2(dva[k][0].z, dva[k][0].w),
                pk2(dva[k][1].x, dva[k][1].y), pk2(dva[k][1].z, dva[k][1].w) };
    *(uint4*)(detB + dpos[k] * 64 + ((dcp[k] ^ ((dpos[k] >> 1) & 3)) << 4)) = w;
  }
  if (tid < 64) {
    uint4 w = { pk2(dva[3][0].x, dva[3][0].y), pk2(dva[3][0].z, dva[3][0].w),
                pk2(dva[3][1].x, dva[3][1].y), pk2(dva[3][1].z, dva[3][1].w) };
    *(uint4*)(detB + dpos[3] * 64 + ((dcp[3] ^ ((dpos[3] >> 1) & 3)) << 4)) = w;
  }
  if (tid < 320) {
    char* base = tmpB + t_ij * (OPAD * 64);
    #pragma unroll
    for (int k = 0; k < 4; ++k) {
      int o = t_oq * 4 + k;
      uint4 w;
      #define COMP(V) ((k == 0) ? (V).x : (k == 1) ? (V).y : (k == 2) ? (V).z : (V).w)
      w.x = pk2(COMP(tv[0]), COMP(tv[1]));
      w.y = pk2(COMP(tv[2]), COMP(tv[3]));
      w.z = pk2(COMP(tv[4]), COMP(tv[5]));
      w.w = pk2(COMP(tv[6]), COMP(tv[7]));
      #undef COMP
      *(uint4*)(base + o * 64 + ((t_co ^ ((o >> 1) & 3)) << 4)) = w;
    }
  }

  __syncthreads();

  // ---- compute ----
  const int w    = tid >> 6;
  const int lane = tid & 63;
  const int lo   = lane & 15;
  const int hi   = lane >> 4;
  const int nm   = (w < 3) ? 3 : 2;

  int posb[3];
  #pragma unroll
  for (int mi = 0; mi < 3; ++mi) {
    int m = w + mi * 8;
    int p = m * 16 + lo;
    if (p > NP - 1) p = NP - 1;
    posb[mi] = (p / 17) * 20 + (p % 17);
  }

  f32x4 acc[3][2] = {};

  const int o0r  = lo;
  const int o1r  = (16 + lo < NO) ? (16 + lo) : (NO - 1);
  const int bad0 = o0r * 64 + ((hi ^ ((o0r >> 1) & 3)) << 4);
  const int bad1 = o1r * 64 + ((hi ^ ((o1r >> 1) & 3)) << 4);

  for (int ij = 0; ij < 16; ++ij) {
    const int sh = (ij >> 2) * 20 + (ij & 3);

    bf16x8 bf0 = *(const bf16x8*)(tmpB + bad0 + ij * (OPAD * 64));
    bf16x8 bf1 = *(const bf16x8*)(tmpB + bad1 + ij * (OPAD * 64));

    #pragma unroll
    for (int mi = 0; mi < 3; ++mi) {
      if (mi < nm) {
        int pos  = posb[mi] + sh;
        int byte = pos * 64 + ((hi ^ ((pos >> 1) & 3)) << 4);
        bf16x8 a = *(const bf16x8*)(detB + byte);
        acc[mi][0] = __builtin_amdgcn_mfma_f32_16x16x32_bf16(a, bf0, acc[mi][0], 0, 0, 0);
        acc[mi][1] = __builtin_amdgcn_mfma_f32_16x16x32_bf16(a, bf1, acc[mi][1], 0, 0, 0);
      }
    }
  }

  unsigned short* __restrict__ pws = ws + ((size_t)q * NB + b) * (NO * NPP);
  #pragma unroll
  for (int mi = 0; mi < 3; ++mi) {
    if (mi < nm) {
      int p0 = (w + mi * 8) * 16 + hi * 4;
      #pragma unroll
      for (int n = 0; n < 2; ++n) {
        int o = n * 16 + lo;
        if (o < NO) {
          if (p0 + 4 <= NP) {
            uint2 val = { pk2(acc[mi][n][0], acc[mi][n][1]),
                          pk2(acc[mi][n][2], acc[mi][n][3]) };
            *(uint2*)(pws + o * NPP + p0) = val;
          } else if (p0 < NP) {
            pws[o * NPP + p0] = bfbits(acc[mi][n][0]);
          }
        }
      }
    }
  }
}

// ---- PROBE: staging phase only, asm-keepalive, no global writes ----
__global__ __launch_bounds__(512, 2)
void stage_only_kernel(const float* __restrict__ det,
                       const float* __restrict__ tmp) {
  __shared__ alignas(16) char lds[DET_LDS_BYTES + TMP_LDS_BYTES];
  char* detB = lds;
  char* tmpB = lds + DET_LDS_BYTES;

  const int tid = threadIdx.x;
  const int b   = blockIdx.x >> 3;
  const int q   = blockIdx.x & 7;
  const int c0  = q * CQ;

  const float* __restrict__ dsrc = det + (size_t)b * (NPOS * C_TOT) + c0;
  const float* __restrict__ tsrc = tmp + (size_t)b * (16 * C_TOT * NO);

  float4 dva[4][2];
  int dpos[4] = {0, 0, 0, 0}, dcp[4] = {0, 0, 0, 0};
  #pragma unroll
  for (int k = 0; k < 3; ++k) {
    int u = tid + k * 512;
    dpos[k] = u >> 2; dcp[k] = u & 3;
    const float* s = dsrc + dpos[k] * C_TOT + dcp[k] * 8;
    dva[k][0] = *(const float4*)s;
    dva[k][1] = *(const float4*)(s + 4);
  }
  if (tid < 64) {
    int u = 1536 + tid;
    dpos[3] = u >> 2; dcp[3] = u & 3;
    const float* s = dsrc + dpos[3] * C_TOT + dcp[3] * 8;
    dva[3][0] = *(const float4*)s;
    dva[3][1] = *(const float4*)(s + 4);
  }
  int t_ij = 0, t_co = 0, t_oq = 0;
  float4 tv[8];
  if (tid < 320) {
    t_ij = tid / 20;
    int r = tid - t_ij * 20;
    t_co = r / 5;
    t_oq = r - t_co * 5;
    const float* s = tsrc + t_ij * (C_TOT * NO) + (c0 + t_co * 8) * NO + t_oq * 4;
    #pragma unroll
    for (int rr = 0; rr < 8; ++rr) tv[rr] = *(const float4*)(s + rr * NO);
  }

  #pragma unroll
  for (int k = 0; k < 3; ++k) {
    uint4 w = { pk2(dva[k][0].x, dva[k][0].y), pk2(dva[k][0].z, dva[k][0].w),
                pk2(dva[k][1].x, dva[k][1].y), pk2(dva[k][1].z, dva[k][1].w) };
    *(uint4*)(detB + dpos[k] * 64 + ((dcp[k] ^ ((dpos[k] >> 1) & 3)) << 4)) = w;
  }
  if (tid < 64) {
    uint4 w = { pk2(dva[3][0].x, dva[3][0].y), pk2(dva[3][0].z, dva[3][0].w),
                pk2(dva[3][1].x, dva[3][1].y), pk2(dva[3][1].z, dva[3][1].w) };
    *(uint4*)(detB + dpos[3] * 64 + ((dcp[3] ^ ((dpos[3] >> 1) & 3)) << 4)) = w;
  }
  if (tid < 320) {
    char* base = tmpB + t_ij * (OPAD * 64);
    #pragma unroll
    for (int k = 0; k < 4; ++k) {
      int o = t_oq * 4 + k;
      uint4 w;
      #define COMP(V) ((k == 0) ? (V).x : (k == 1) ? (V).y : (k == 2) ? (V).z : (V).w)
      w.x = pk2(COMP(tv[0]), COMP(tv[1]));
      w.y = pk2(COMP(tv[2]), COMP(tv[3]));
      w.z = pk2(COMP(tv[4]), COMP(tv[5]));
      w.w = pk2(COMP(tv[6]), COMP(tv[7]));
      #undef COMP
      *(uint4*)(base + o * 64 + ((t_co ^ ((o >> 1) & 3)) << 4)) = w;
    }
  }

  __syncthreads();

  // keepalive: read back a dword per thread from each region so the
  // ds_writes can't be dead-store-eliminated; no global output.
  unsigned v1 = *(volatile unsigned*)(detB + tid * 4);
  unsigned v2 = *(volatile unsigned*)(tmpB + tid * 4);
  asm volatile("" :: "v"(v1), "v"(v2));
}

extern "C" void kernel_launch(void* const* d_in, const int* in_sizes, int n_in,
                              void* d_out, int out_size, void* d_ws, size_t ws_size,
                              hipStream_t stream) {
  (void)in_sizes; (void)n_in; (void)out_size; (void)ws_size;
  const float* det = (const float*)d_in[0];
  const float* tmp = (const float*)d_in[1];
  float* out = (float*)d_out;
  unsigned short* ws = (unsigned short*)d_ws;   // 6.06 MB partials

  siamese_kernel<<<dim3(NB * NQ), dim3(512), 0, stream>>>(det, tmp, ws);
  reduce_kernel<<<dim3(NB * 4), dim3(256), 0, stream>>>(ws, out);
  // PROBE: 4x staging-only. Delta vs R10 = 4 x (T_stage + node).
  stage_only_kernel<<<dim3(NB * NQ), dim3(512), 0, stream>>>(det, tmp);
  stage_only_kernel<<<dim3(NB * NQ), dim3(512), 0, stream>>>(det, tmp);
  stage_only_kernel<<<dim3(NB * NQ), dim3(512), 0, stream>>>(det, tmp);
  stage_only_kernel<<<dim3(NB * NQ), dim3(512), 0, stream>>>(det, tmp);
}

// Round 14
// 23.611 us; speedup vs baseline: 2.2879x; 2.2879x over previous
//
#include <hip/hip_runtime.h>
#include <hip/hip_bf16.h>

// SiameseConv: out[b,y,x,o] = sum_{i,j,c} det[b,y+i,x+j,c] * tmpl[b,i,j,c,o]
// det: [64,20,20,256] f32, tmpl: [64,4,4,256*20] f32, out: [64,17,17,20] f32.
//
// R13 probe decomposition of 21.9us: stage 6.2 (memory floor ~7.6TB/s) +
// compute 11.2 + reduce 0.8 + 2 nodes 3.7. Stage->barrier->compute lockstep
// (all blocks stage together) => VMEM never overlaps LDS/MFMA. R5/R12 showed
// occupancy doesn't change compute -> pipeline INTRA-block.
// R14: persistent 2-unit blocks. Grid 256 (1/CU, 92KB LDS = 2 buffers); block
// processes (b,q) then (b+32,q). stage u0; barrier; ISSUE u1 global loads ->
// regs; compute u0 (fetch1 hides under it); write regs->buf1; barrier;
// compute u1. T14 issue-early/write-late, overlap by construction.

typedef __bf16 bf16x8 __attribute__((ext_vector_type(8)));
typedef float f32x4 __attribute__((ext_vector_type(4)));

#define NB 64
#define C_TOT 256
#define CQ 32            // channels per block-unit
#define NQ 8             // c-chunks
#define NPOS 400         // 20*20 det positions
#define NP 289           // 17*17 output positions
#define NPP 296          // padded p stride in bf16 partials
#define NO 20            // outputs per position
#define OPAD 20          // o rows in LDS tmpl tile
#define QSTRIDE (NB * NO * NPP)             // elems per q slice = 378880
#define DET_LDS_BYTES (NPOS * CQ * 2)       // 25600: [400 pos][32 c]
#define TMP_LDS_BYTES (16 * OPAD * CQ * 2)  // 20480: [16 ij][20 o][32 c]
#define BUF_BYTES (DET_LDS_BYTES + TMP_LDS_BYTES)   // 46080

__device__ __forceinline__ unsigned short bfbits(float f) {
  __bf16 h = (__bf16)f;
  return __builtin_bit_cast(unsigned short, h);
}
__device__ __forceinline__ unsigned pk2(float a, float b) {
  return (unsigned)bfbits(a) | ((unsigned)bfbits(b) << 16);
}
__device__ __forceinline__ float lo2f(unsigned u) {
  return __builtin_bit_cast(float, u << 16);
}
__device__ __forceinline__ float hi2f(unsigned u) {
  return __builtin_bit_cast(float, u & 0xFFFF0000u);
}

// ---- reduce: out[b,p,o] = sum_q bf16 ws[q,b,o,p]; transpose via LDS ----
__global__ __launch_bounds__(256)
void reduce_kernel(const unsigned short* __restrict__ ws, float* __restrict__ out) {
  __shared__ float sbuf[NO * 80];   // [o][80 p]
  const int b    = blockIdx.x >> 2;
  const int pg   = blockIdx.x & 3;
  const int p0g  = pg * 80;
  const int np   = (NP - p0g < 80) ? (NP - p0g) : 80;   // 80,80,80,49
  const int noct = (np + 7) >> 3;                       // 10 or 7
  const int units = NO * noct;                          // 200 or 140

  const int t = threadIdx.x;
  if (t < units) {
    int o  = t / noct;
    int po = t - o * noct;
    const unsigned short* src = ws + ((size_t)b * NO + o) * NPP + p0g + po * 8;
    float s[8] = {0, 0, 0, 0, 0, 0, 0, 0};
    #pragma unroll
    for (int q = 0; q < NQ; ++q) {
      uint4 v = *(const uint4*)(src + (size_t)q * QSTRIDE);
      s[0] += lo2f(v.x); s[1] += hi2f(v.x);
      s[2] += lo2f(v.y); s[3] += hi2f(v.y);
      s[4] += lo2f(v.z); s[5] += hi2f(v.z);
      s[6] += lo2f(v.w); s[7] += hi2f(v.w);
    }
    #pragma unroll
    for (int j = 0; j < 8; ++j) sbuf[o * 80 + po * 8 + j] = s[j];
  }
  __syncthreads();

  for (int p = t; p < np; p += 256) {
    float* dst = out + (size_t)b * (NP * NO) + (p0g + p) * NO;
    #pragma unroll
    for (int k = 0; k < 5; ++k) {
      f32x4 v;
      #pragma unroll
      for (int j = 0; j < 4; ++j) v[j] = sbuf[(k * 4 + j) * 80 + p];
      *(f32x4*)(dst + k * 4) = v;
    }
  }
}

struct StageRegs {
  float4 dva[4][2];   // det: 3x512 units + tail (tid<64)
  float4 tv[8];       // tmpl: tid<320
};

__device__ __forceinline__ void stage_load(const float* __restrict__ dsrc,
                                           const float* __restrict__ tsrc,
                                           int tid, int c0, StageRegs& r) {
  #pragma unroll
  for (int k = 0; k < 3; ++k) {
    int u = tid + k * 512;
    const float* s = dsrc + (u >> 2) * C_TOT + (u & 3) * 8;
    r.dva[k][0] = *(const float4*)s;
    r.dva[k][1] = *(const float4*)(s + 4);
  }
  if (tid < 64) {
    int u = 1536 + tid;
    const float* s = dsrc + (u >> 2) * C_TOT + (u & 3) * 8;
    r.dva[3][0] = *(const float4*)s;
    r.dva[3][1] = *(const float4*)(s + 4);
  }
  if (tid < 320) {
    int t_ij = tid / 20;
    int rr_  = tid - t_ij * 20;
    int t_co = rr_ / 5;
    int t_oq = rr_ - t_co * 5;
    const float* s = tsrc + t_ij * (C_TOT * NO) + (c0 + t_co * 8) * NO + t_oq * 4;
    #pragma unroll
    for (int rr = 0; rr < 8; ++rr) r.tv[rr] = *(const float4*)(s + rr * NO);
  }
}

__device__ __forceinline__ void stage_write(char* __restrict__ detB,
                                            char* __restrict__ tmpB,
                                            int tid, const StageRegs& r) {
  #pragma unroll
  for (int k = 0; k < 3; ++k) {
    int u = tid + k * 512;
    int pos = u >> 2, cp = u & 3;
    uint4 w = { pk2(r.dva[k][0].x, r.dva[k][0].y), pk2(r.dva[k][0].z, r.dva[k][0].w),
                pk2(r.dva[k][1].x, r.dva[k][1].y), pk2(r.dva[k][1].z, r.dva[k][1].w) };
    *(uint4*)(detB + pos * 64 + ((cp ^ ((pos >> 1) & 3)) << 4)) = w;
  }
  if (tid < 64) {
    int u = 1536 + tid;
    int pos = u >> 2, cp = u & 3;
    uint4 w = { pk2(r.dva[3][0].x, r.dva[3][0].y), pk2(r.dva[3][0].z, r.dva[3][0].w),
                pk2(r.dva[3][1].x, r.dva[3][1].y), pk2(r.dva[3][1].z, r.dva[3][1].w) };
    *(uint4*)(detB + pos * 64 + ((cp ^ ((pos >> 1) & 3)) << 4)) = w;
  }
  if (tid < 320) {
    int t_ij = tid / 20;
    int rr_  = tid - t_ij * 20;
    int t_co = rr_ / 5;
    int t_oq = rr_ - t_co * 5;
    char* base = tmpB + t_ij * (OPAD * 64);
    #pragma unroll
    for (int k = 0; k < 4; ++k) {
      int o = t_oq * 4 + k;
      uint4 w;
      #define COMP(V) ((k == 0) ? (V).x : (k == 1) ? (V).y : (k == 2) ? (V).z : (V).w)
      w.x = pk2(COMP(r.tv[0]), COMP(r.tv[1]));
      w.y = pk2(COMP(r.tv[2]), COMP(r.tv[3]));
      w.z = pk2(COMP(r.tv[4]), COMP(r.tv[5]));
      w.w = pk2(COMP(r.tv[6]), COMP(r.tv[7]));
      #undef COMP
      *(uint4*)(base + o * 64 + ((t_co ^ ((o >> 1) & 3)) << 4)) = w;
    }
  }
}

__device__ __forceinline__ void compute_unit(const char* __restrict__ detB,
                                             const char* __restrict__ tmpB,
                                             int w, int lo, int hi, int nm,
                                             const int posb[3], int bad0, int bad1,
                                             unsigned short* __restrict__ pws) {
  f32x4 acc[3][2] = {};

  for (int ij = 0; ij < 16; ++ij) {
    const int sh = (ij >> 2) * 20 + (ij & 3);

    bf16x8 bf0 = *(const bf16x8*)(tmpB + bad0 + ij * (OPAD * 64));
    bf16x8 bf1 = *(const bf16x8*)(tmpB + bad1 + ij * (OPAD * 64));

    #pragma unroll
    for (int mi = 0; mi < 3; ++mi) {
      if (mi < nm) {
        int pos  = posb[mi] + sh;
        int byte = pos * 64 + ((hi ^ ((pos >> 1) & 3)) << 4);
        bf16x8 a = *(const bf16x8*)(detB + byte);
        acc[mi][0] = __builtin_amdgcn_mfma_f32_16x16x32_bf16(a, bf0, acc[mi][0], 0, 0, 0);
        acc[mi][1] = __builtin_amdgcn_mfma_f32_16x16x32_bf16(a, bf1, acc[mi][1], 0, 0, 0);
      }
    }
  }

  // C/D frag: col(o)=lane&15, row(p)=(lane>>4)*4+reg -> reg v is contiguous p.
  #pragma unroll
  for (int mi = 0; mi < 3; ++mi) {
    if (mi < nm) {
      int p0 = (w + mi * 8) * 16 + hi * 4;
      #pragma unroll
      for (int n = 0; n < 2; ++n) {
        int o = n * 16 + lo;
        if (o < NO) {
          if (p0 + 4 <= NP) {
            uint2 val = { pk2(acc[mi][n][0], acc[mi][n][1]),
                          pk2(acc[mi][n][2], acc[mi][n][3]) };
            *(uint2*)(pws + o * NPP + p0) = val;
          } else if (p0 < NP) {   // p0 == 288: single last position
            pws[o * NPP + p0] = bfbits(acc[mi][n][0]);
          }
        }
      }
    }
  }
}

__global__ __launch_bounds__(512, 2)
void siamese_kernel(const float* __restrict__ det,
                    const float* __restrict__ tmp,
                    unsigned short* __restrict__ ws) {
  __shared__ alignas(16) char lds[2 * BUF_BYTES];   // 92160 B (gfx950: 160K/CU)

  const int tid = threadIdx.x;
  const int u0  = blockIdx.x;        // 0..255
  const int b0  = u0 >> 3;           // 0..31
  const int q   = u0 & 7;
  const int b1  = b0 + 32;
  const int c0  = q * CQ;

  const float* dsrc0 = det + (size_t)b0 * (NPOS * C_TOT) + c0;
  const float* tsrc0 = tmp + (size_t)b0 * (16 * C_TOT * NO);
  const float* dsrc1 = det + (size_t)b1 * (NPOS * C_TOT) + c0;
  const float* tsrc1 = tmp + (size_t)b1 * (16 * C_TOT * NO);

  // ---- stage unit0 ----
  {
    StageRegs r0;
    stage_load(dsrc0, tsrc0, tid, c0, r0);
    stage_write(lds, lds + DET_LDS_BYTES, tid, r0);
  }
  __syncthreads();

  // ---- issue unit1 loads NOW (waitcnt lands at stage_write(r1) below) ----
  StageRegs r1;
  stage_load(dsrc1, tsrc1, tid, c0, r1);

  // ---- compute setup (shared) ----
  const int w    = tid >> 6;
  const int lane = tid & 63;
  const int lo   = lane & 15;
  const int hi   = lane >> 4;
  const int nm   = (w < 3) ? 3 : 2;   // tiles m = w + 8*mi: 3/3/3/2x5 = 19

  int posb[3];
  #pragma unroll
  for (int mi = 0; mi < 3; ++mi) {
    int m = w + mi * 8;
    int p = m * 16 + lo;
    if (p > NP - 1) p = NP - 1;        // clamp pad rows (masked at store)
    posb[mi] = (p / 17) * 20 + (p % 17);
  }
  const int o0r  = lo;
  const int o1r  = (16 + lo < NO) ? (16 + lo) : (NO - 1);  // clamp pad cols
  const int bad0 = o0r * 64 + ((hi ^ ((o0r >> 1) & 3)) << 4);
  const int bad1 = o1r * 64 + ((hi ^ ((o1r >> 1) & 3)) << 4);

  // ---- compute unit0 (unit1 fetch in flight underneath) ----
  compute_unit(lds, lds + DET_LDS_BYTES, w, lo, hi, nm, posb, bad0, bad1,
               ws + ((size_t)q * NB + b0) * (NO * NPP));

  // ---- write unit1 to buffer 1, then compute it ----
  stage_write(lds + BUF_BYTES, lds + BUF_BYTES + DET_LDS_BYTES, tid, r1);
  __syncthreads();

  compute_unit(lds + BUF_BYTES, lds + BUF_BYTES + DET_LDS_BYTES, w, lo, hi, nm,
               posb, bad0, bad1,
               ws + ((size_t)q * NB + b1) * (NO * NPP));
}

extern "C" void kernel_launch(void* const* d_in, const int* in_sizes, int n_in,
                              void* d_out, int out_size, void* d_ws, size_t ws_size,
                              hipStream_t stream) {
  (void)in_sizes; (void)n_in; (void)out_size; (void)ws_size;
  const float* det = (const float*)d_in[0];
  const float* tmp = (const float*)d_in[1];
  float* out = (float*)d_out;
  unsigned short* ws = (unsigned short*)d_ws;   // 6.06 MB partials

  siamese_kernel<<<dim3(NB * NQ / 2), dim3(512), 0, stream>>>(det, tmp, ws);
  reduce_kernel<<<dim3(NB * 4), dim3(256), 0, stream>>>(ws, out);
}